// Round 1
// baseline (71447.723 us; speedup 1.0000x reference)
//
#include <hip/hip_runtime.h>
#include <cstdint>

constexpr int B   = 32;
constexpr int ET  = 1024;   // enc_T
constexpr int DT  = 1024;   // dec_T
constexpr int D   = 256;
constexpr int KW  = 31;
constexpr int PAD = 15;
constexpr int PT  = ET + 2*PAD; // 1054, zero-padded halo

// ws layout (floats)
constexpr size_t PBUF_OFF = 0;                         // [B][2][PT]  prev,cum (padded)
constexpr size_t U_OFF    = PBUF_OFF + (size_t)B*2*PT; // [B][D]      u = mel_t*mask + att_out
constexpr size_t E_OFF    = U_OFF + (size_t)B*D;       // [B][ET]     energies

__global__ __launch_bounds__(256) void k_init(const float* __restrict__ mel,
                                              const int* __restrict__ olen,
                                              float* __restrict__ ws) {
  int i0 = blockIdx.x*256 + threadIdx.x;
  int stride = gridDim.x*256;
  for (int i = i0; i < B*2*PT; i += stride) ws[PBUF_OFF + i] = 0.f;
  for (int i = i0; i < B*D; i += stride) {
    int b = i >> 8; int d = i & 255;
    float dm = (0 < olen[b]) ? 1.f : 0.f;   // step-0 dec mask
    ws[U_OFF + i] = mel[(size_t)b*DT*D + d] * dm;   // att_out starts at 0
  }
}

// energies[b,t] = sum_d v[d] * tanh(u[b,d] + sum_{c,k} W[d,c,k]*p[b,c,t+k-PAD])
__global__ __launch_bounds__(512) void k_energies(
    const float* __restrict__ W,      // [D][2][KW]
    const float* __restrict__ v,      // [D]
    const float* __restrict__ u,      // [B][D]
    const float* __restrict__ pbuf,   // [B][2][PT]
    float* __restrict__ energies) {   // [B][ET]
  const int b    = blockIdx.y;
  const int tile = blockIdx.x;
  const int tid  = threadIdx.x;
  const int tt   = tid & 127;
  const int dq   = __builtin_amdgcn_readfirstlane(tid >> 7); // wave-uniform d-quarter
  const int t    = tile*128 + tt;

  // per-thread conv windows in VGPRs (pbuf is halo-padded so index is just t+k)
  const float* p0 = pbuf + ((size_t)b*2)*PT + t;
  float pa[KW], pc[KW];
#pragma unroll
  for (int k = 0; k < KW; ++k) { pa[k] = p0[k]; pc[k] = p0[PT + k]; }

  const float* ub = u + (size_t)b*D;
  float e = 0.f;
  for (int i = 0; i < 64; ++i) {
    const int d = dq*64 + i;                  // scalar (dq SGPR, i uniform)
    const float* wr = W + d*(2*KW);
    float s0 = ub[d], s1 = 0.f, s2 = 0.f, s3 = 0.f;   // 4 accumulators: break dep chain
#pragma unroll
    for (int k = 0; k < 15; ++k) {
      s0 = fmaf(wr[2*k],      pa[2*k],   s0);
      s1 = fmaf(wr[2*k+1],    pa[2*k+1], s1);
      s2 = fmaf(wr[KW+2*k],   pc[2*k],   s2);
      s3 = fmaf(wr[KW+2*k+1], pc[2*k+1], s3);
    }
    s0 = fmaf(wr[30],    pa[30], s0);
    s2 = fmaf(wr[KW+30], pc[30], s2);
    float s = (s0 + s1) + (s2 + s3);
    // tanh(s) = 1 - 2/(exp(2s)+1); overflow-safe (exp->inf => 1, exp->0 => -1)
    float ex = __expf(2.f*s);
    float th = fmaf(-2.f, __builtin_amdgcn_rcpf(ex + 1.f), 1.f);
    e = fmaf(v[d], th, e);
  }

  __shared__ float part[4][128];
  part[dq][tt] = e;
  __syncthreads();
  if (tid < 128) {
    float et = (part[0][tid] + part[1][tid]) + (part[2][tid] + part[3][tid]);
    energies[(size_t)b*ET + tile*128 + tid] = et;
  }
}

// softmax over full ET (pads included, like reference), mask AFTER; update state;
// att_out = score @ enc; write outputs; precompute u for step+1.
__global__ __launch_bounds__(256) void k_step2(
    const float* __restrict__ energies, // [B][ET]
    const float* __restrict__ enc,      // [B][ET][D]
    const float* __restrict__ mel,      // [B][DT][D]
    const int* __restrict__ elen,
    const int* __restrict__ olen,
    float* __restrict__ pbuf,           // [B][2][PT]
    float* __restrict__ u,              // [B][D]
    float* __restrict__ out_att,        // [B][DT][D]
    float* __restrict__ out_sc,         // [B][DT][ET]
    int step) {
  const int b   = blockIdx.x;
  const int tid = threadIdx.x;
  __shared__ float sc[ET];
  __shared__ float red[8];

  float e4[4];
  float mx = -3.4e38f;
#pragma unroll
  for (int j = 0; j < 4; ++j) {
    e4[j] = energies[(size_t)b*ET + tid + j*256];
    mx = fmaxf(mx, e4[j]);
  }
#pragma unroll
  for (int m = 1; m < 64; m <<= 1) mx = fmaxf(mx, __shfl_xor(mx, m, 64));
  if ((tid & 63) == 0) red[tid >> 6] = mx;
  __syncthreads();
  mx = fmaxf(fmaxf(red[0], red[1]), fmaxf(red[2], red[3]));

  float ssum = 0.f;
#pragma unroll
  for (int j = 0; j < 4; ++j) { e4[j] = __expf(e4[j] - mx); ssum += e4[j]; }
#pragma unroll
  for (int m = 1; m < 64; m <<= 1) ssum += __shfl_xor(ssum, m, 64);
  if ((tid & 63) == 0) red[4 + (tid >> 6)] = ssum;
  __syncthreads();
  float S = (red[4] + red[5]) + (red[6] + red[7]);
  float inv = 1.f / S;
  const int L = elen[b];
#pragma unroll
  for (int j = 0; j < 4; ++j) {
    int t = tid + j*256;
    float val = e4[j] * inv;
    if (t >= L) val = 0.f;       // pad mask AFTER softmax (matches reference)
    sc[t] = val;
  }
  __syncthreads();

#pragma unroll
  for (int j = 0; j < 4; ++j) {
    int t = tid + j*256;
    float val = sc[t];
    pbuf[((size_t)b*2)*PT + PAD + t]     = val;    // prev score
    pbuf[((size_t)b*2 + 1)*PT + PAD + t] += val;   // cumulative
    out_sc[((size_t)b*DT + step)*ET + t] = val;    // att_scores output
  }

  // att_out[b, d=tid] = sum_t sc[t] * enc[b,t,d]   (coalesced over d)
  float a0 = 0.f, a1 = 0.f, a2 = 0.f, a3 = 0.f;
  const float* eb = enc + (size_t)b*ET*D + tid;
  for (int t2 = 0; t2 < ET; t2 += 4) {
    a0 = fmaf(sc[t2+0], eb[(size_t)(t2+0)*D], a0);
    a1 = fmaf(sc[t2+1], eb[(size_t)(t2+1)*D], a1);
    a2 = fmaf(sc[t2+2], eb[(size_t)(t2+2)*D], a2);
    a3 = fmaf(sc[t2+3], eb[(size_t)(t2+3)*D], a3);
  }
  float acc = (a0 + a1) + (a2 + a3);               // new_out (carried UNmasked)
  float dm = (step < olen[b]) ? 1.f : 0.f;
  out_att[((size_t)b*DT + step)*D + tid] = acc * dm;  // output masked

  if (step + 1 < DT) {
    float dm1 = (step + 1 < olen[b]) ? 1.f : 0.f;
    u[(size_t)b*D + tid] = fmaf(mel[((size_t)b*DT + step + 1)*D + tid], dm1, acc);
  }
}

extern "C" void kernel_launch(void* const* d_in, const int* in_sizes, int n_in,
                              void* d_out, int out_size, void* d_ws, size_t ws_size,
                              hipStream_t stream) {
  const float* enc = (const float*)d_in[0];
  const float* mel = (const float*)d_in[1];
  const int* elen  = (const int*)d_in[2];
  const int* olen  = (const int*)d_in[3];
  const float* vw  = (const float*)d_in[4];   // [1, D]
  const float* W   = (const float*)d_in[5];   // [D, 2, KW]

  float* out_att = (float*)d_out;                     // [B, DT, D]
  float* out_sc  = out_att + (size_t)B*DT*D;          // [B, DT, ET]
  float* ws = (float*)d_ws;

  k_init<<<128, 256, 0, stream>>>(mel, olen, ws);
  for (int step = 0; step < DT; ++step) {
    k_energies<<<dim3(ET/128, B), 512, 0, stream>>>(
        W, vw, ws + U_OFF, ws + PBUF_OFF, ws + E_OFF);
    k_step2<<<B, 256, 0, stream>>>(
        ws + E_OFF, enc, mel, elen, olen,
        ws + PBUF_OFF, ws + U_OFF, out_att, out_sc, step);
  }
}

// Round 3
// 33858.112 us; speedup vs baseline: 2.1102x; 2.1102x over previous
//
#include <hip/hip_runtime.h>
#include <cstdint>

constexpr int B   = 32;
constexpr int ET  = 1024;
constexpr int DT  = 1024;
constexpr int D   = 256;
constexpr int KW  = 31;
constexpr int PAD = 15;
constexpr int PT  = ET + 2*PAD; // 1054 halo-padded

// ws layout (floats)
constexpr size_t PBUF_OFF = 0;                          // [B][2][PT]
constexpr size_t U_OFF    = PBUF_OFF + (size_t)B*2*PT;  // [B][D]
constexpr size_t E_OFF    = U_OFF + (size_t)B*D;        // [B][ET]
constexpr size_t WT_OFF   = E_OFF + (size_t)B*ET;       // [62][D] transposed conv weights
constexpr size_t VSUM_OFF = WT_OFF + (size_t)62*D;      // scalar sum(v)

__global__ __launch_bounds__(256) void k_init(const float* __restrict__ mel,
                                              const int* __restrict__ olen,
                                              const float* __restrict__ W,
                                              const float* __restrict__ v,
                                              float* __restrict__ ws) {
  int i0 = blockIdx.x*256 + threadIdx.x;
  int stride = gridDim.x*256;
  for (int i = i0; i < B*2*PT; i += stride) ws[PBUF_OFF + i] = 0.f;
  for (int i = i0; i < B*D; i += stride) {
    int b = i >> 8, d = i & 255;
    float dm = (0 < olen[b]) ? 1.f : 0.f;
    ws[U_OFF + i] = mel[(size_t)b*DT*D + d] * dm;
  }
  for (int i = i0; i < 62*D; i += stride) {           // W_T[k][d] = W[d][k]
    int k = i >> 8, d = i & 255;
    ws[WT_OFF + i] = W[d*62 + k];
  }
  if (i0 == 0) { float a = 0.f; for (int d = 0; d < D; ++d) a += v[d]; ws[VSUM_OFF] = a; }
}

// intra-wave butterfly add via DPP (VALU pipe, avoids shared DS pipe)
template <int CTRL>
__device__ __forceinline__ float dpp_add(float x) {
  int y = __builtin_amdgcn_update_dpp(0, __float_as_int(x), CTRL, 0xF, 0xF, false);
  return x + __int_as_float(y);
}

// lane = d layout: W row resident in 62 VGPRs; window in 32-slot circular VGPR
// buffer (unroll-32 -> static indices); per-t reduce over 64 d-lanes via DPP.
__global__ __launch_bounds__(256) void k_energies(
    const float* __restrict__ WT,     // [62][D]
    const float* __restrict__ v,      // [D]
    const float* __restrict__ u,      // [B][D]
    const float* __restrict__ pbuf,   // [B][2][PT]
    const float* __restrict__ vsum,
    float* __restrict__ energies) {   // [B][ET]
  const int b = blockIdx.y, tile = blockIdx.x;  // 16 tiles x 64 t
  const int tid = threadIdx.x;                  // d = tid
  const int lane = tid & 63, w = tid >> 6;
  const int t0 = tile * 64;

  __shared__ float s_pa[96], s_pc[96];
  __shared__ __align__(16) float s_part[64][20]; // 16 partials per t, padded row

  if (tid < 96) {
    int ix = t0 + tid; if (ix > PT-1) ix = PT-1;      // tail slot unused by math
    const float* pb = pbuf + (size_t)b*2*PT;
    s_pa[tid] = pb[ix];
    s_pc[tid] = pb[PT + ix];
  }
  float wr[62];
#pragma unroll
  for (int k = 0; k < 62; ++k) wr[k] = WT[k*D + tid]; // coalesced
  const float vd = v[tid];
  const float ud = u[b*D + tid];
  __syncthreads();

  float pa[32], pc[32];
#pragma unroll
  for (int k = 0; k < 31; ++k) { pa[k] = s_pa[k]; pc[k] = s_pc[k]; }

#pragma unroll 1
  for (int tb = 0; tb < 64; tb += 32) {
#pragma unroll
    for (int m = 0; m < 32; ++m) {
      const int tt = tb + m;
      float s0 = ud, s1 = 0.f, s2 = 0.f, s3 = 0.f;    // 4 chains: hide FMA latency
#pragma unroll
      for (int k = 0; k < 15; ++k) {
        s0 = fmaf(wr[2*k],      pa[(m+2*k)&31],   s0);
        s1 = fmaf(wr[2*k+1],    pa[(m+2*k+1)&31], s1);
        s2 = fmaf(wr[31+2*k],   pc[(m+2*k)&31],   s2);
        s3 = fmaf(wr[31+2*k+1], pc[(m+2*k+1)&31], s3);
      }
      s0 = fmaf(wr[30], pa[(m+30)&31], s0);
      s2 = fmaf(wr[61], pc[(m+30)&31], s2);
      float s = (s0 + s1) + (s2 + s3);
      // sum_d v*tanh(s) = Vsum - 2*sum_d v*rcp(exp(2s)+1); exp(2s)=exp2(s*2/ln2)
      float ex = __builtin_amdgcn_exp2f(s * 2.885390081777927f);
      float y  = vd * __builtin_amdgcn_rcpf(ex + 1.f);
      y = dpp_add<0xB1>(y);   // quad_perm(1,0,3,2): + lane^1
      y = dpp_add<0x4E>(y);   // quad_perm(2,3,0,1): + lane^2
      y = dpp_add<0x141>(y);  // row_half_mirror:    + lane^7 (== ^4 here)
      y = dpp_add<0x140>(y);  // row_mirror:         + lane^15 (== ^8 here)
      if ((lane & 15) == 0) s_part[tt][(w << 2) | (lane >> 4)] = y;
      // slide window: slot (m+31)&31 <- next p value (static idx under unroll)
      pa[(m+31)&31] = s_pa[tt + 31];
      pc[(m+31)&31] = s_pc[tt + 31];
    }
  }
  __syncthreads();
  if (tid < 64) {
    const float4 r0 = *(const float4*)&s_part[tid][0];
    const float4 r1 = *(const float4*)&s_part[tid][4];
    const float4 r2 = *(const float4*)&s_part[tid][8];
    const float4 r3 = *(const float4*)&s_part[tid][12];
    float e = ((r0.x+r0.y)+(r0.z+r0.w)) + ((r1.x+r1.y)+(r1.z+r1.w))
            + ((r2.x+r2.y)+(r2.z+r2.w)) + ((r3.x+r3.y)+(r3.z+r3.w));
    energies[(size_t)b*ET + t0 + tid] = vsum[0] - 2.f*e;
  }
}

// 256 blocks = 8 d-chunks x 32 batches (XCD-swizzled); softmax replicated per
// chunk; chunk 0 writes scores/state; each chunk computes 32 d of att_out + u.
__global__ __launch_bounds__(256) void k_step2(
    const float* __restrict__ energies, const float* __restrict__ enc,
    const float* __restrict__ mel, const int* __restrict__ elen,
    const int* __restrict__ olen,
    float* __restrict__ pbuf, float* __restrict__ u,
    float* __restrict__ out_att, float* __restrict__ out_sc, int step) {
  const int f = blockIdx.x;
  const int xcd = f & 7, j = f >> 3;
  const int b = xcd + ((j & 3) << 3);   // batch b's 8 chunk-blocks share an XCD
  const int chunk = j >> 2;
  const int tid = threadIdx.x;
  __shared__ float sc[ET];
  __shared__ float red[8];
  __shared__ float ra[8][32];

  float e4[4];
  float mx = -3.4e38f;
#pragma unroll
  for (int q = 0; q < 4; ++q) {
    e4[q] = energies[(size_t)b*ET + tid + q*256];
    mx = fmaxf(mx, e4[q]);
  }
#pragma unroll
  for (int m = 1; m < 64; m <<= 1) mx = fmaxf(mx, __shfl_xor(mx, m, 64));
  if ((tid & 63) == 0) red[tid >> 6] = mx;
  __syncthreads();
  mx = fmaxf(fmaxf(red[0], red[1]), fmaxf(red[2], red[3]));
  float ssum = 0.f;
#pragma unroll
  for (int q = 0; q < 4; ++q) { e4[q] = __expf(e4[q] - mx); ssum += e4[q]; }
#pragma unroll
  for (int m = 1; m < 64; m <<= 1) ssum += __shfl_xor(ssum, m, 64);
  if ((tid & 63) == 0) red[4 + (tid >> 6)] = ssum;
  __syncthreads();
  float inv = 1.f / ((red[4] + red[5]) + (red[6] + red[7]));
  const int L = elen[b];
#pragma unroll
  for (int q = 0; q < 4; ++q) {
    int t = tid + q*256;
    float val = e4[q] * inv;
    if (t >= L) val = 0.f;               // mask AFTER softmax (reference order)
    sc[t] = val;
  }
  __syncthreads();

  if (chunk == 0) {
    float* pprev = pbuf + (size_t)b*2*PT + PAD;
    float* pcum  = pprev + PT;
#pragma unroll
    for (int q = 0; q < 4; ++q) {
      int t = tid + q*256;
      float val = sc[t];
      pprev[t] = val;
      pcum[t] += val;
      out_sc[((size_t)b*DT + step)*ET + t] = val;
    }
  }

  // att_out for d in [chunk*32, chunk*32+32)
  const int dl = tid & 31, tg = tid >> 5;
  const float* eb = enc + (size_t)b*ET*D + chunk*32 + dl;
  float a0 = 0.f, a1 = 0.f, a2 = 0.f, a3 = 0.f;
  for (int t = tg; t < ET; t += 32) {
    a0 = fmaf(sc[t],      eb[(size_t)t*D],        a0);
    a1 = fmaf(sc[t+8],    eb[(size_t)(t+8)*D],    a1);
    a2 = fmaf(sc[t+16],   eb[(size_t)(t+16)*D],   a2);
    a3 = fmaf(sc[t+24],   eb[(size_t)(t+24)*D],   a3);
  }
  ra[tg][dl] = (a0 + a1) + (a2 + a3);
  __syncthreads();
  if (tid < 32) {
    float acc = 0.f;
#pragma unroll
    for (int g = 0; g < 8; ++g) acc += ra[g][tid];
    int d = chunk*32 + tid;
    float dm = (step < olen[b]) ? 1.f : 0.f;
    out_att[((size_t)b*DT + step)*D + d] = acc * dm;
    if (step + 1 < DT) {
      float dm1 = (step + 1 < olen[b]) ? 1.f : 0.f;
      u[(size_t)b*D + d] = fmaf(mel[((size_t)b*DT + step + 1)*D + d], dm1, acc);
    }
  }
}

extern "C" void kernel_launch(void* const* d_in, const int* in_sizes, int n_in,
                              void* d_out, int out_size, void* d_ws, size_t ws_size,
                              hipStream_t stream) {
  const float* enc = (const float*)d_in[0];
  const float* mel = (const float*)d_in[1];
  const int* elen  = (const int*)d_in[2];
  const int* olen  = (const int*)d_in[3];
  const float* vw  = (const float*)d_in[4];   // [1, D]
  const float* W   = (const float*)d_in[5];   // [D, 2, KW]

  float* out_att = (float*)d_out;                 // [B, DT, D]
  float* out_sc  = out_att + (size_t)B*DT*D;      // [B, DT, ET]
  float* ws = (float*)d_ws;

  k_init<<<128, 256, 0, stream>>>(mel, olen, W, vw, ws);
  for (int step = 0; step < DT; ++step) {
    k_energies<<<dim3(16, 32), 256, 0, stream>>>(
        ws + WT_OFF, vw, ws + U_OFF, ws + PBUF_OFF, ws + VSUM_OFF, ws + E_OFF);
    k_step2<<<256, 256, 0, stream>>>(
        ws + E_OFF, enc, mel, elen, olen,
        ws + PBUF_OFF, ws + U_OFF, out_att, out_sc, step);
  }
}